// Round 1
// baseline (158.160 us; speedup 1.0000x reference)
//
#include <hip/hip_runtime.h>
#include <math.h>

#define H 512
#define W 512
#define TX 32
#define TY 32
#define SX 44                  // staged width: cols [2,44) used, float4-aligned window trick
#define NPIX (32LL*512*512)

// order-preserving float->uint encoding so we can use native atomicMax(u32).
// enc is monotone; enc(x) > 0 for all reals, so a 0-initialized slot acts as -inf.
__device__ inline unsigned encf(float f) {
    unsigned u = __float_as_uint(f);
    return (u & 0x80000000u) ? ~u : (u | 0x80000000u);
}
__device__ inline float decf(unsigned e) {
    unsigned u = (e & 0x80000000u) ? (e ^ 0x80000000u) : ~e;
    return __uint_as_float(u);
}

__global__ __launch_bounds__(256) void maxred_kernel(
        const float* __restrict__ in, const float* __restrict__ tg,
        const float* __restrict__ mk, unsigned* __restrict__ mx) {
    const float4* in4 = (const float4*)in;
    const float4* tg4 = (const float4*)tg;
    const float4* mk4 = (const float4*)mk;
    long long n4 = NPIX / 4;
    long long idx = (long long)blockIdx.x * blockDim.x + threadIdx.x;
    long long stride = (long long)gridDim.x * blockDim.x;
    float ma = -INFINITY, mb = -INFINITY;   // two independent chains
    for (long long i = idx; i < n4; i += stride) {
        float4 a = in4[i], b = tg4[i], c = mk4[i];
        ma = fmaxf(ma, fmaxf(fmaxf(a.x * c.x, a.y * c.y), fmaxf(a.z * c.z, a.w * c.w)));
        mb = fmaxf(mb, fmaxf(fmaxf(b.x * c.x, b.y * c.y), fmaxf(b.z * c.z, b.w * c.w)));
    }
    float m = fmaxf(ma, mb);
    #pragma unroll
    for (int off = 32; off; off >>= 1) m = fmaxf(m, __shfl_down(m, off, 64));
    __shared__ float smax[4];
    int lane = threadIdx.x & 63, wid = threadIdx.x >> 6;
    if (lane == 0) smax[wid] = m;
    __syncthreads();
    if (threadIdx.x == 0) {
        float r = fmaxf(fmaxf(smax[0], smax[1]), fmaxf(smax[2], smax[3]));
        atomicMax(mx, encf(r));
    }
}

__global__ __launch_bounds__(256, 4) void ssim_kernel(
        const float* __restrict__ in, const float* __restrict__ tg,
        const float* __restrict__ mk, const float* __restrict__ win,
        const unsigned* __restrict__ mxp, double* __restrict__ sum) {
    __shared__ __align__(16) float vch[6][TY][SX];   // vertically blurred {m,a,b,aa,bb,ab}
    __shared__ float gw[11];
    __shared__ float ssum[4];

    int t = threadIdx.x;
    if (t < 11) {
        float s = 0.f;
        #pragma unroll
        for (int j = 0; j < 11; j++) s += win[t * 11 + j];
        gw[t] = s;   // separable 1-D gaussian (row sums of outer(g,g); sum==1)
    }
    // uniform scalar: issue early, used only in the epilogue
    float L = decf(*mxp);
    float C3 = 0.5f * (0.03f * L) * (0.03f * L);
    __syncthreads();

    // hoist blur weights into SGPRs: frees ~11 VGPRs for load pipelining,
    // and each fma reads one sgpr operand (legal: 1 sgpr per VALU instr).
    float wk[11];
    #pragma unroll
    for (int k = 0; k < 11; k++)
        wk[k] = __uint_as_float(__builtin_amdgcn_readfirstlane(__float_as_uint(gw[k])));

    int img = blockIdx.z;
    int y0 = blockIdx.y * TY, x0 = blockIdx.x * TX;
    const size_t base = (size_t)img * H * W;
    const float* inb = in + base;
    const float* tgb = tg + base;
    const float* mkb = mk + base;

    // ---- vertical blur: 168 tasks = 42 columns x 4 strips of 8 output rows ----
    if (t < 168) {
        int s = t / 42, cc = t - s * 42;       // strip, staged column
        int x = x0 - 5 + cc;
        bool inx = (unsigned)x < (unsigned)W;
        int xc = inx ? x : 0;                  // clamped: loads always legal
        float xs = inx ? 1.f : 0.f;            // zero-pad applied once at the write
        int ybase = y0 + 8 * s - 5;
        float acc[6][8];
        #pragma unroll
        for (int ch = 0; ch < 6; ch++)
            #pragma unroll
            for (int u = 0; u < 8; u++) acc[ch][u] = 0.f;

        if (ybase >= 0 && ybase <= H - 18) {
            // fast interior path: no y checks, no exec-mask juggling,
            // strength-reduced addressing, unconditional loads.
            size_t g = (size_t)ybase * W + xc;
            #pragma unroll
            for (int j = 0; j < 18; j++) {
                float m = mkb[g], iv = inb[g], tv = tgb[g];
                g += W;
                float a = iv * m, b = tv * m;
                float v[6] = { m, a, b, a * a, b * b, a * b };
                #pragma unroll
                for (int u = 0; u < 8; u++) {
                    int k = j - u;
                    if (k >= 0 && k < 11) {   // compile-time pruned after unroll
                        float w = wk[k];
                        #pragma unroll
                        for (int ch = 0; ch < 6; ch++)
                            acc[ch][u] = fmaf(w, v[ch], acc[ch][u]);
                    }
                }
            }
        } else {
            // y-edge path (only y0==0 / y0==480 strips): clamped addr + cndmask zeroing
            #pragma unroll
            for (int j = 0; j < 18; j++) {
                int y = ybase + j;
                bool yok = (unsigned)y < (unsigned)H;
                size_t g = (size_t)(yok ? y : 0) * W + xc;
                float sc = yok ? 1.f : 0.f;
                float m = mkb[g] * sc, iv = inb[g] * sc, tv = tgb[g] * sc;
                float a = iv * m, b = tv * m;
                float v[6] = { m, a, b, a * a, b * b, a * b };
                #pragma unroll
                for (int u = 0; u < 8; u++) {
                    int k = j - u;
                    if (k >= 0 && k < 11) {
                        float w = wk[k];
                        #pragma unroll
                        for (int ch = 0; ch < 6; ch++)
                            acc[ch][u] = fmaf(w, v[ch], acc[ch][u]);
                    }
                }
            }
        }
        #pragma unroll
        for (int u = 0; u < 8; u++) {
            int rr = 8 * s + u;
            #pragma unroll
            for (int ch = 0; ch < 6; ch++) vch[ch][rr][cc + 2] = acc[ch][u] * xs;
        }
    }
    __syncthreads();

    // ---- horizontal blur + structure map: thread -> (row, 4 consecutive cols) ----
    int r = t >> 3, c0 = (t & 7) << 2;
    float hs[6][4];
    #pragma unroll
    for (int ch = 0; ch < 6; ch++) {
        float Wl[16];
        #pragma unroll
        for (int q = 0; q < 4; q++) {
            float4 v = *(const float4*)&vch[ch][r][c0 + 4 * q];
            Wl[4 * q + 0] = v.x; Wl[4 * q + 1] = v.y;
            Wl[4 * q + 2] = v.z; Wl[4 * q + 3] = v.w;
        }
        #pragma unroll
        for (int u = 0; u < 4; u++) {
            float h = 0.f;
            #pragma unroll
            for (int k = 0; k < 11; k++) h = fmaf(wk[k], Wl[u + 2 + k], h);
            hs[ch][u] = h;
        }
    }

    // structure map with num/den multiplied through by mw^2:
    //   num = hs5*mw - hs1*hs2 + C3*mw^2
    //   den = sqrt(Xi*Xt) + (C3+1e-8)*mw^2,  Xi = max(hs3*mw - hs1^2,0) + 1e-12*mw^2
    // exactly equivalent to the reference up to fp rounding; hw rcp/sqrt ~1 ulp.
    float lsum = 0.f;
    #pragma unroll
    for (int u = 0; u < 4; u++) {
        float h1 = hs[1][u], h2 = hs[2][u];
        float mw = hs[0][u] + 1e-8f;
        float mw2 = mw * mw;
        float e12 = 1e-12f * mw2;
        float Xi = fmaxf(fmaf(hs[3][u], mw, -h1 * h1), 0.f) + e12;
        float Xt = fmaxf(fmaf(hs[4][u], mw, -h2 * h2), 0.f) + e12;
        float num = fmaf(hs[5][u], mw, -h1 * h2) + C3 * mw2;
        float den = __builtin_amdgcn_sqrtf(Xi * Xt) + (C3 + 1e-8f) * mw2;
        lsum += num * __builtin_amdgcn_rcpf(den);
    }

    #pragma unroll
    for (int off = 32; off; off >>= 1) lsum += __shfl_down(lsum, off, 64);
    int lane = t & 63, wid = t >> 6;
    if (lane == 0) ssum[wid] = lsum;
    __syncthreads();
    if (t == 0) {
        float tot = ssum[0] + ssum[1] + ssum[2] + ssum[3];
        atomicAdd(sum, (double)tot);
    }
}

__global__ void fin_kernel(const double* __restrict__ sum, float* __restrict__ out) {
    out[0] = 1.0f - (float)(*sum / (double)NPIX);
}

extern "C" void kernel_launch(void* const* d_in, const int* in_sizes, int n_in,
                              void* d_out, int out_size, void* d_ws, size_t ws_size,
                              hipStream_t stream) {
    const float* in  = (const float*)d_in[0];
    const float* tg  = (const float*)d_in[1];
    const float* mk  = (const float*)d_in[2];
    const float* win = (const float*)d_in[3];
    float* out = (float*)d_out;

    double*   dsum = (double*)d_ws;
    unsigned* dmax = (unsigned*)((char*)d_ws + 8);

    // dsum = 0.0, dmax = 0 (order-encoding floor) in one stream-ordered memset
    hipMemsetAsync(d_ws, 0, 12, stream);
    maxred_kernel<<<2048, 256, 0, stream>>>(in, tg, mk, dmax);
    ssim_kernel<<<dim3(16, 16, 32), 256, 0, stream>>>(in, tg, mk, win, dmax, dsum);
    fin_kernel<<<1, 1, 0, stream>>>(dsum, out);
}